// Round 1
// baseline (67306.689 us; speedup 1.0000x reference)
//
#include <hip/hip_runtime.h>
#include <math.h>

#define TSTEPS 512
#define NBATCH 256
#define DLL 300
#define DAA 74
#define DVV 35
#define DX  409
#define DH  128
#define DMEM 256
#define CST 768   // 6*DH

typedef unsigned short u16;
typedef unsigned int   u32;

__device__ __forceinline__ float bf(const u16* __restrict__ p, int i){
  return __uint_as_float(((u32)p[i]) << 16);
}
__device__ __forceinline__ float sigf(float x){ return 1.0f/(1.0f+expf(-x)); }

// dst[k*OUT + o] = bf16(src[o*IN + k])   (transpose to [K][OUT] for coalesced GEMV)
__global__ void cast_transpose(const float* __restrict__ src, u16* __restrict__ dst,
                               int OUT, int IN){
  int idx = blockIdx.x*blockDim.x + threadIdx.x;
  int total = OUT*IN;
  if (idx >= total) return;
  int k = idx / OUT;
  int o = idx - k*OUT;
  float v = src[o*IN + k];
  u32 u = __float_as_uint(v);
  u32 r = (u + 0x7fffu + ((u>>16)&1u)) >> 16;   // RNE
  dst[idx] = (u16)r;
}

struct P {
  const float* x;
  const float *bih_l,*bhh_l,*bih_a,*bhh_a,*bih_v,*bhh_v;
  const float *a1b1,*a1b2,*a2b1,*a2b2,*g1b1,*g1b2,*g2b1,*g2b2;
  const float *ob1,*ow2,*ob2;
  const u16 *ihl,*hhl,*iha,*hha,*ihv,*hhv;
  const u16 *a1w1,*a1w2,*a2w1,*a2w2,*g1w1,*g1w2,*g2w1,*g2w2,*ow1;
  float* out;
};

__device__ __forceinline__ void lstm_cell(
    const float* __restrict__ sx, int xoff, int din,
    float* __restrict__ sh, float* __restrict__ sc,
    float* __restrict__ cs_new,
    const u16* __restrict__ wih, const u16* __restrict__ whh,
    const float* __restrict__ bih, const float* __restrict__ bhh,
    float* __restrict__ sg, int tid)
{
  const int o1 = tid + 256;
  float a0 = bih[tid] + bhh[tid];
  float a1 = bih[o1]  + bhh[o1];
  #pragma unroll 8
  for (int k=0;k<din;k++){
    float xv = sx[xoff+k];
    a0 += xv*bf(wih, k*512+tid);
    a1 += xv*bf(wih, k*512+o1);
  }
  #pragma unroll 8
  for (int k=0;k<DH;k++){
    float hv = sh[k];
    a0 += hv*bf(whh, k*512+tid);
    a1 += hv*bf(whh, k*512+o1);
  }
  sg[tid]=a0; sg[o1]=a1;
  __syncthreads();
  if (tid < DH){
    float ig = sigf(sg[tid]);
    float fg = sigf(sg[DH+tid]);
    float gg = tanhf(sg[2*DH+tid]);
    float og = sigf(sg[3*DH+tid]);
    float c  = fg*sc[tid] + ig*gg;
    float h  = og*tanhf(c);
    sc[tid]=c; sh[tid]=h; cs_new[tid]=c;
  }
  __syncthreads();
}

__global__ __launch_bounds__(256)
void mfn_persistent(P p){
  __shared__ float s_x[DX];
  __shared__ float s_hl[DH], s_ha[DH], s_hv[DH];
  __shared__ float s_cl[DH], s_ca[DH], s_cv[DH];
  __shared__ float s_mem[DMEM];
  __shared__ float s_cstar[CST];
  __shared__ float s_att[CST];
  __shared__ float s_z[CST];
  __shared__ float s_g[512];
  __shared__ float s_red[4];

  const int tid = threadIdx.x;
  const int n   = blockIdx.x;

  if (tid < DH){ s_hl[tid]=0.f; s_ha[tid]=0.f; s_hv[tid]=0.f;
                 s_cl[tid]=0.f; s_ca[tid]=0.f; s_cv[tid]=0.f; }
  s_mem[tid]=0.f;
  __syncthreads();

  for (int t=0; t<TSTEPS; t++){
    // ---- load x_t row; stash prev cell states into cStar[0:384] ----
    {
      const float* xr = p.x + ((size_t)t*NBATCH + n)*DX;
      for (int i=tid; i<DX; i+=256) s_x[i] = xr[i];
      if (tid < DH){
        s_cstar[tid]        = s_cl[tid];
        s_cstar[DH+tid]     = s_ca[tid];
        s_cstar[2*DH+tid]   = s_cv[tid];
      }
    }
    __syncthreads();

    // ---- 3 LSTM cells; new cells go to cStar[384:768] ----
    lstm_cell(s_x, 0,        DLL, s_hl, s_cl, s_cstar+3*DH, p.ihl, p.hhl, p.bih_l, p.bhh_l, s_g, tid);
    lstm_cell(s_x, DLL,      DAA, s_ha, s_ca, s_cstar+4*DH, p.iha, p.hha, p.bih_a, p.bhh_a, s_g, tid);
    lstm_cell(s_x, DLL+DAA,  DVV, s_hv, s_cv, s_cstar+5*DH, p.ihv, p.hhv, p.bih_v, p.bhh_v, s_g, tid);

    // ---- attention layer 1: z1 = relu(cStar @ att1_W1.T + b1), 256 outs ----
    {
      float acc = p.a1b1[tid];
      #pragma unroll 8
      for (int k=0;k<CST;k++) acc += s_cstar[k]*bf(p.a1w1, k*256+tid);
      s_z[tid] = fmaxf(acc, 0.f);
    }
    __syncthreads();

    // ---- attention layer 2 (768 outs) + softmax + attended ----
    {
      float sc0=p.a1b2[tid], sc1=p.a1b2[tid+256], sc2=p.a1b2[tid+512];
      #pragma unroll 8
      for (int k=0;k<256;k++){
        float zv = s_z[k];
        sc0 += zv*bf(p.a1w2, k*768+tid);
        sc1 += zv*bf(p.a1w2, k*768+tid+256);
        sc2 += zv*bf(p.a1w2, k*768+tid+512);
      }
      float m = fmaxf(fmaxf(sc0,sc1),sc2);
      for (int off=32; off; off>>=1) m = fmaxf(m, __shfl_down(m, off));
      if ((tid&63)==0) s_red[tid>>6]=m;
      __syncthreads();
      m = fmaxf(fmaxf(s_red[0],s_red[1]), fmaxf(s_red[2],s_red[3]));
      float e0=expf(sc0-m), e1=expf(sc1-m), e2=expf(sc2-m);
      float s = e0+e1+e2;
      for (int off=32; off; off>>=1) s += __shfl_down(s, off);
      __syncthreads();                    // all reads of s_red (max) done
      if ((tid&63)==0) s_red[tid>>6]=s;
      __syncthreads();
      float inv = 1.0f/(s_red[0]+s_red[1]+s_red[2]+s_red[3]);
      s_att[tid]     = e0*inv*s_cstar[tid];
      s_att[tid+256] = e1*inv*s_cstar[tid+256];
      s_att[tid+512] = e2*inv*s_cstar[tid+512];
    }
    __syncthreads();

    // ---- att2 l1 + g1 l1 + g2 l1 (relu), inputs attended(768) [+ mem(256) for g] ----
    {
      float u =p.a2b1[tid], v1=p.g1b1[tid], v2=p.g2b1[tid];
      #pragma unroll 8
      for (int k=0;k<CST;k++){
        float a = s_att[k];
        u  += a*bf(p.a2w1, k*256+tid);
        v1 += a*bf(p.g1w1, k*256+tid);
        v2 += a*bf(p.g2w1, k*256+tid);
      }
      #pragma unroll 8
      for (int k=0;k<DMEM;k++){
        float mv = s_mem[k];
        v1 += mv*bf(p.g1w1, (CST+k)*256+tid);
        v2 += mv*bf(p.g2w1, (CST+k)*256+tid);
      }
      s_z[tid]      = fmaxf(u ,0.f);
      s_z[256+tid]  = fmaxf(v1,0.f);
      s_z[512+tid]  = fmaxf(v2,0.f);
    }
    __syncthreads();

    // ---- layer 2s: cHat=tanh, gamma1/2=sigmoid; mem update ----
    {
      float ch=p.a2b2[tid], gm1=p.g1b2[tid], gm2=p.g2b2[tid];
      #pragma unroll 8
      for (int k=0;k<DMEM;k++){
        ch  += s_z[k]      * bf(p.a2w2, k*256+tid);
        gm1 += s_z[256+k]  * bf(p.g1w2, k*256+tid);
        gm2 += s_z[512+k]  * bf(p.g2w2, k*256+tid);
      }
      ch = tanhf(ch); gm1 = sigf(gm1); gm2 = sigf(gm2);
      s_mem[tid] = gm1*s_mem[tid] + gm2*ch;
    }
    __syncthreads();
  }

  // ---- output MLP: last_hs = [h_l, h_a, h_v, mem] (640) ----
  {
    float acc = p.ob1[tid];
    #pragma unroll 8
    for (int k=0;k<DH;k++)   acc += s_hl[k]*bf(p.ow1, k*256+tid);
    #pragma unroll 8
    for (int k=0;k<DH;k++)   acc += s_ha[k]*bf(p.ow1, (DH+k)*256+tid);
    #pragma unroll 8
    for (int k=0;k<DH;k++)   acc += s_hv[k]*bf(p.ow1, (2*DH+k)*256+tid);
    #pragma unroll 8
    for (int k=0;k<DMEM;k++) acc += s_mem[k]*bf(p.ow1, (3*DH+k)*256+tid);
    acc = fmaxf(acc, 0.f);
    float pp = acc * p.ow2[tid];
    for (int off=32; off; off>>=1) pp += __shfl_down(pp, off);
    if ((tid&63)==0) s_red[tid>>6]=pp;
    __syncthreads();
    if (tid==0) p.out[n] = s_red[0]+s_red[1]+s_red[2]+s_red[3] + p.ob2[0];
  }
}

extern "C" void kernel_launch(void* const* d_in, const int* in_sizes, int n_in,
                              void* d_out, int out_size, void* d_ws, size_t ws_size,
                              hipStream_t stream){
  u16* ws = (u16*)d_ws;
  struct M { int src; size_t off; int OUT, IN; };
  const M mats[15] = {
    { 5,       0, 512,  300},   // Wih_l
    { 6,  153600, 512,  128},   // Whh_l
    { 9,  219136, 512,   74},   // Wih_a
    {10,  257024, 512,  128},   // Whh_a
    {13,  322560, 512,   35},   // Wih_v
    {14,  340480, 512,  128},   // Whh_v
    {17,  406016, 256,  768},   // att1_W1
    {19,  602624, 768,  256},   // att1_W2
    {21,  799232, 256,  768},   // att2_W1
    {23,  995840, 256,  256},   // att2_W2
    {25, 1061376, 256, 1024},   // g1_W1
    {27, 1323520, 256,  256},   // g1_W2
    {29, 1389056, 256, 1024},   // g2_W1
    {31, 1651200, 256,  256},   // g2_W2
    {33, 1716736, 256,  640},   // out_W1
  };
  for (int i=0;i<15;i++){
    int total = mats[i].OUT*mats[i].IN;
    cast_transpose<<<(total+255)/256, 256, 0, stream>>>(
        (const float*)d_in[mats[i].src], ws + mats[i].off, mats[i].OUT, mats[i].IN);
  }

  P p;
  p.x     = (const float*)d_in[0];
  p.bih_l = (const float*)d_in[7];  p.bhh_l = (const float*)d_in[8];
  p.bih_a = (const float*)d_in[11]; p.bhh_a = (const float*)d_in[12];
  p.bih_v = (const float*)d_in[15]; p.bhh_v = (const float*)d_in[16];
  p.a1b1  = (const float*)d_in[18]; p.a1b2  = (const float*)d_in[20];
  p.a2b1  = (const float*)d_in[22]; p.a2b2  = (const float*)d_in[24];
  p.g1b1  = (const float*)d_in[26]; p.g1b2  = (const float*)d_in[28];
  p.g2b1  = (const float*)d_in[30]; p.g2b2  = (const float*)d_in[32];
  p.ob1   = (const float*)d_in[34]; p.ow2   = (const float*)d_in[35];
  p.ob2   = (const float*)d_in[36];
  p.ihl   = ws + 0;       p.hhl  = ws + 153600;
  p.iha   = ws + 219136;  p.hha  = ws + 257024;
  p.ihv   = ws + 322560;  p.hhv  = ws + 340480;
  p.a1w1  = ws + 406016;  p.a1w2 = ws + 602624;
  p.a2w1  = ws + 799232;  p.a2w2 = ws + 995840;
  p.g1w1  = ws + 1061376; p.g1w2 = ws + 1323520;
  p.g2w1  = ws + 1389056; p.g2w2 = ws + 1651200;
  p.ow1   = ws + 1716736;
  p.out   = (float*)d_out;

  mfn_persistent<<<NBATCH, 256, 0, stream>>>(p);
}